// Round 6
// baseline (280.188 us; speedup 1.0000x reference)
//
#include <hip/hip_runtime.h>

// expRNN/modReLU recurrence, B=8192, T=784, I=1, H=30, C=10.
//
// Round 6: split-precision bf16 MFMA (3-term exact truncation splits).
//   z = W·h_aug per step as v_mfma_f32_16x16x32_bf16, 16 batches/wave.
//   - Numerics: truncation split h=h1+h2+h3, W=w1+w2+w3 (bit-slices, exact;
//     residuals 2^-8/2^-16/2^-24). 6 product terms (11,12,21,22,13,31)
//     => per-step injected error ~2^-23. Calibrated vs measured f32 run
//     (absmax = threshold/25 at q=6e-8): predicted absmax ~2x f32 ~ 1.6e29.
//   - Layout: A-frags hold W rows interleaved so that C-layout
//     (col=lane&15,row=quad*4+i) == next step's B-layout
//     (n=lane&15,k=quad*8+j): A1 rows {8q..8q+3}, A2 rows {8q+4..8q+7}.
//     Lane ends each step holding h rows 8q..8q+7 of batch lane&15 —
//     exactly its next B fragment. NO cross-lane exchange at all.
//   - x_t in augmented slot h[30] (quad 3, elem 6); W col 30 = W_ih,
//     col 31 = 0; rows 30,31 of W and b are 0 so pads self-maintain.
//   - 512 blocks x 1 wave x 16 batches = 8192. MFMA pipe does the MACs;
//     VALU per iter ~83 instr (modrelu + splits + packs).

#define T_STEPS 784
#define NBATCH  8192
#define NH      30
#define NC      10
#define BPW     16    // batches per wave
#define XPAD    788   // padded x row (bank spread; 2-way max = free)

typedef short bf16x8 __attribute__((ext_vector_type(8)));
typedef float f32x4  __attribute__((ext_vector_type(4)));

#define MFMA(acc, a, b) \
    acc = __builtin_amdgcn_mfma_f32_16x16x32_bf16(a, b, acc, 0, 0, 0)

__device__ __forceinline__ float truncbf(float x) {
    return __int_as_float(__float_as_int(x) & 0xFFFF0000);
}
// pack bf16(lo), bf16(hi) (= hi16 bit-slices) into one dword
__device__ __forceinline__ unsigned pack2(float lo, float hi) {
    return __builtin_amdgcn_perm(__float_as_uint(hi), __float_as_uint(lo),
                                 0x07060302u);
}
__device__ __forceinline__ bf16x8 pack8(const float* v) {
    union { unsigned u[4]; bf16x8 b; } o;
    o.u[0] = pack2(v[0], v[1]);
    o.u[1] = pack2(v[2], v[3]);
    o.u[2] = pack2(v[4], v[5]);
    o.u[3] = pack2(v[6], v[7]);
    return o.b;
}

__global__ __launch_bounds__(64, 1)
void rnn_modrelu_mfma(const float* __restrict__ inp,    // [B, T, 1]
                      const float* __restrict__ W_ih,   // [H, 1]
                      const float* __restrict__ W_hh,   // [H, H]
                      const float* __restrict__ b_mod,  // [H]
                      const float* __restrict__ W_lin,  // [C, H]
                      const float* __restrict__ b_lin,  // [C]
                      float* __restrict__ out)          // [B, C]
{
    __shared__ __align__(16) float xl[BPW * XPAD];   // 50.4 KB
    __shared__ float hf[BPW * 32];

    const int l   = threadIdx.x;
    const int blk = blockIdx.x;
    const int m   = l & 15;     // batch column (C col / B col / A row idx)
    const int q   = l >> 4;     // quad: owns h rows 8q..8q+7, A cols 8q..8q+7

    // ---- preload x: 16 batches x 784 floats, coalesced, padded rows ----
    {
        const float4* src = (const float4*)(inp + (size_t)blk * (BPW * T_STEPS));
        #pragma unroll
        for (int k = 0; k < 49; ++k) {
            int v = l + 64 * k;                 // < 3136 float4
            if (v < (BPW * T_STEPS) / 4) {
                int b   = v / 196;
                int rem = v - b * 196;
                *(float4*)(xl + b * XPAD + 4 * rem) = src[v];
            }
        }
    }

    // ---- A fragments: W rows interleaved, 3 split terms, 2 row-groups ----
    // A[m_idx][k=q*8+j]; actual W row for grp g: 8*(m>>2) + (m&3) + 4*g.
    bf16x8 afr[2][3];
    #pragma unroll
    for (int g = 0; g < 2; ++g) {
        const int row = 8 * (m >> 2) + (m & 3) + 4 * g;
        float wv[8], r1v[8], r2v[8];
        #pragma unroll
        for (int j = 0; j < 8; ++j) {
            const int col = q * 8 + j;
            float v = 0.0f;
            if (row < NH) {
                if (col < NH)       v = W_hh[row * NH + col];
                else if (col == NH) v = W_ih[row];      // x coefficient
            }
            wv[j]  = v;
            r1v[j] = v - truncbf(v);
            r2v[j] = r1v[j] - truncbf(r1v[j]);
        }
        afr[g][0] = pack8(wv);
        afr[g][1] = pack8(r1v);
        afr[g][2] = pack8(r2v);
    }

    // modReLU bias for owned rows 8q..8q+7 (pad rows -> 0)
    float bmv[8];
    #pragma unroll
    for (int i = 0; i < 8; ++i) {
        const int row = 8 * q + i;
        bmv[i] = (row < NH) ? b_mod[row] : 0.0f;
    }

    __syncthreads();

    const float* xb = xl + m * XPAD;

    // ---- initial h: zeros + x_0 in slot 30 (quad 3, elem 6) ----
    float hval[8];
    #pragma unroll
    for (int i = 0; i < 8; ++i) hval[i] = 0.0f;
    if (q == 3) hval[6] = xb[0];

    bf16x8 bf1, bf2, bf3;
    {
        float r1v[8], r2v[8];
        #pragma unroll
        for (int j = 0; j < 8; ++j) {
            r1v[j] = hval[j] - truncbf(hval[j]);
            r2v[j] = r1v[j] - truncbf(r1v[j]);
        }
        bf1 = pack8(hval); bf2 = pack8(r1v); bf3 = pack8(r2v);
    }

    // ---- recurrence ----
    #pragma unroll 1
    for (int t = 0; t < T_STEPS; ++t) {
        f32x4 c0a = {0.f,0.f,0.f,0.f}, c0b = {0.f,0.f,0.f,0.f};
        f32x4 c1a = {0.f,0.f,0.f,0.f}, c1b = {0.f,0.f,0.f,0.f};

        // 6 precision terms x 2 row-groups, 4 independent 3-deep chains
        MFMA(c0a, afr[0][0], bf1);   // w1*h1
        MFMA(c1a, afr[1][0], bf1);
        MFMA(c0b, afr[0][1], bf1);   // w2*h1
        MFMA(c1b, afr[1][1], bf1);
        MFMA(c0a, afr[0][0], bf2);   // w1*h2
        MFMA(c1a, afr[1][0], bf2);
        MFMA(c0b, afr[0][1], bf2);   // w2*h2
        MFMA(c1b, afr[1][1], bf2);
        MFMA(c0a, afr[0][0], bf3);   // w1*h3
        MFMA(c1a, afr[1][0], bf3);
        MFMA(c0b, afr[0][2], bf1);   // w3*h1
        MFMA(c1b, afr[1][2], bf1);

        int tn = t + 1; if (tn >= T_STEPS) tn = T_STEPS - 1;
        const float xnext = xb[tn];   // broadcast ds_read

        // z -> modReLU -> h_{t+1} (rows 8q+i); pad rows stay 0
        #pragma unroll
        for (int i = 0; i < 4; ++i) {
            const float z0 = c0a[i] + c0b[i];
            const float z1 = c1a[i] + c1b[i];
            hval[i]     = copysignf(fmaxf(fabsf(z0) + bmv[i],     0.0f), z0);
            hval[4 + i] = copysignf(fmaxf(fabsf(z1) + bmv[4 + i], 0.0f), z1);
        }
        if (q == 3) hval[6] = xnext;  // slot 30 carries x_{t+1}

        // exact 3-term split + bf16 pack -> next B fragments
        float r1v[8], r2v[8];
        #pragma unroll
        for (int j = 0; j < 8; ++j) {
            r1v[j] = hval[j] - truncbf(hval[j]);
            r2v[j] = r1v[j] - truncbf(r1v[j]);
        }
        bf1 = pack8(hval); bf2 = pack8(r1v); bf3 = pack8(r2v);
    }

    // ---- stash h (rows < 30) for classifier ----
    #pragma unroll
    for (int i = 0; i < 8; ++i) {
        const int row = 8 * q + i;
        if (row < NH) hf[m * 32 + row] = hval[i];
    }
    __syncthreads();

    // ---- classifier: 160 outputs (16 batches x 10 classes) ----
    #pragma unroll
    for (int it = 0; it < 3; ++it) {
        const int k = l + 64 * it;
        if (k < BPW * NC) {
            const int b = k / NC;
            const int c = k % NC;
            float acc = b_lin[c];
            #pragma unroll
            for (int i = 0; i < NH; ++i) {
                acc = fmaf(W_lin[c * NH + i], hf[b * 32 + i], acc);
            }
            out[((size_t)blk * BPW + b) * NC + c] = acc;
        }
    }
}

extern "C" void kernel_launch(void* const* d_in, const int* in_sizes, int n_in,
                              void* d_out, int out_size, void* d_ws, size_t ws_size,
                              hipStream_t stream) {
    const float* inp   = (const float*)d_in[0];
    const float* W_ih  = (const float*)d_in[1];
    const float* W_hh  = (const float*)d_in[2];
    const float* b_mod = (const float*)d_in[3];
    const float* W_lin = (const float*)d_in[4];
    const float* b_lin = (const float*)d_in[5];
    float* out = (float*)d_out;

    dim3 grid(NBATCH / BPW);   // 512 blocks
    dim3 block(64);            // one wave
    rnn_modrelu_mfma<<<grid, block, 0, stream>>>(inp, W_ih, W_hh, b_mod,
                                                 W_lin, b_lin, out);
}